// Round 3
// baseline (347.098 us; speedup 1.0000x reference)
//
#include <hip/hip_runtime.h>
#include <hip/hip_cooperative_groups.h>
#include <cstdint>
#include <cstddef>

namespace cg = cooperative_groups;

typedef _Float16 half_t;
typedef _Float16 half8 __attribute__((ext_vector_type(8)));
typedef float floatx4 __attribute__((ext_vector_type(4)));

#define E_ 8
#define D_ 512
#define H_ 2048
#define NTOK 1024
#define NP 2048          // NTOK * top_k
#define TM 128
#define MAX_TILES 24     // sum ceil(cnt_e/128) <= 16 + 7 = 23

struct Params {
    const float *inp, *gate_w, *gate_b, *w1, *b1, *w2, *b2, *ln_w, *ln_b;
    float *out;
    half_t *W1h, *W2h, *Xg, *Y1;
    float *Y2p, *score;
    int *idx, *pos, *tile_e, *tile_row0, *tile_cnt, *ntiles;
};

__device__ __forceinline__ float gelu_f(float x) {
    return 0.5f * x * (1.0f + erff(x * 0.7071067811865476f));
}

// async global->LDS, 16B/lane; LDS dest = wave-uniform base + lane*16
__device__ __forceinline__ void gload_lds16(const half_t* g, half_t* l) {
    __builtin_amdgcn_global_load_lds(
        (__attribute__((address_space(1))) void*)(g),
        (__attribute__((address_space(3))) void*)(l),
        16, 0, 0);
}

// ---- GEMM1 job: one 128x128 tile of Y1 = gelu(Xg @ W1[e]^T + b1[e]) ----
// BK=64 as two BK=32 panels (keeps global_load_lds lane-contiguity).
__device__ void gemm1_job(const Params& P, half_t* As, half_t* Bs,
                          int t, int cb, int tid) {
    int e = P.tile_e[t], row0 = P.tile_row0[t], cnt = P.tile_cnt[t];
    int colbase = cb * 128;
    int wave = tid >> 6, lane = tid & 63, quad = lane >> 4, l16 = lane & 15;
    int wm = (wave & 1) * 64, wn = (wave >> 1) * 64;
    const half_t* Abase = P.Xg + (size_t)row0 * D_;
    const half_t* Bbase = P.W1h + ((size_t)e * H_ + colbase) * D_;
    int srow = tid >> 2, scol = (tid & 3) * 8;        // seg s adds 64 rows
    floatx4 acc[4][4] = {};
    for (int k0 = 0; k0 < D_; k0 += 64) {
        __syncthreads();
        #pragma unroll
        for (int j = 0; j < 2; j++) {
            #pragma unroll
            for (int s = 0; s < 2; s++) {
                int q = tid + s * 256;
                int row = srow + s * 64;
                gload_lds16(Abase + (size_t)row * D_ + k0 + j * 32 + scol,
                            As + j * 4096 + q * 8);
                gload_lds16(Bbase + (size_t)row * D_ + k0 + j * 32 + scol,
                            Bs + j * 4096 + q * 8);
            }
        }
        __syncthreads();
        #pragma unroll
        for (int j = 0; j < 2; j++) {
            half8 a[4], b[4];
            #pragma unroll
            for (int mi = 0; mi < 4; mi++)
                a[mi] = *(const half8*)(As + j * 4096 + (wm + mi * 16 + l16) * 32 + quad * 8);
            #pragma unroll
            for (int ni = 0; ni < 4; ni++)
                b[ni] = *(const half8*)(Bs + j * 4096 + (wn + ni * 16 + l16) * 32 + quad * 8);
            #pragma unroll
            for (int mi = 0; mi < 4; mi++)
                #pragma unroll
                for (int ni = 0; ni < 4; ni++)
                    acc[mi][ni] = __builtin_amdgcn_mfma_f32_16x16x32_f16(a[mi], b[ni], acc[mi][ni], 0, 0, 0);
        }
    }
    float bias[4];
    #pragma unroll
    for (int ni = 0; ni < 4; ni++)
        bias[ni] = P.b1[(size_t)e * H_ + colbase + wn + ni * 16 + l16];
    #pragma unroll
    for (int mi = 0; mi < 4; mi++) {
        #pragma unroll
        for (int r = 0; r < 4; r++) {
            int rr = wm + mi * 16 + quad * 4 + r;
            if (rr >= cnt) continue;
            size_t rowoff = (size_t)(row0 + rr) * H_;
            #pragma unroll
            for (int ni = 0; ni < 4; ni++) {
                float v = acc[mi][ni][r] + bias[ni];
                P.Y1[rowoff + colbase + wn + ni * 16 + l16] = (half_t)gelu_f(v);
            }
        }
    }
}

// ---- GEMM2 job: 128x128 tile, split-K partial kz of Y2p = Y1 @ W2[e]^T ----
__device__ void gemm2_job(const Params& P, half_t* As, half_t* Bs,
                          int t, int cb, int kz, int tid) {
    int e = P.tile_e[t], row0 = P.tile_row0[t], cnt = P.tile_cnt[t];
    int colbase = cb * 128;
    int kzb = kz * 512;
    int wave = tid >> 6, lane = tid & 63, quad = lane >> 4, l16 = lane & 15;
    int wm = (wave & 1) * 64, wn = (wave >> 1) * 64;
    const half_t* Abase = P.Y1 + (size_t)row0 * H_ + kzb;
    const half_t* Bbase = P.W2h + ((size_t)e * D_ + colbase) * H_ + kzb;
    int srow = tid >> 2, scol = (tid & 3) * 8;
    floatx4 acc[4][4] = {};
    for (int k0 = 0; k0 < 512; k0 += 64) {
        __syncthreads();
        #pragma unroll
        for (int j = 0; j < 2; j++) {
            #pragma unroll
            for (int s = 0; s < 2; s++) {
                int q = tid + s * 256;
                int row = srow + s * 64;
                gload_lds16(Abase + (size_t)row * H_ + k0 + j * 32 + scol,
                            As + j * 4096 + q * 8);
                gload_lds16(Bbase + (size_t)row * H_ + k0 + j * 32 + scol,
                            Bs + j * 4096 + q * 8);
            }
        }
        __syncthreads();
        #pragma unroll
        for (int j = 0; j < 2; j++) {
            half8 a[4], b[4];
            #pragma unroll
            for (int mi = 0; mi < 4; mi++)
                a[mi] = *(const half8*)(As + j * 4096 + (wm + mi * 16 + l16) * 32 + quad * 8);
            #pragma unroll
            for (int ni = 0; ni < 4; ni++)
                b[ni] = *(const half8*)(Bs + j * 4096 + (wn + ni * 16 + l16) * 32 + quad * 8);
            #pragma unroll
            for (int mi = 0; mi < 4; mi++)
                #pragma unroll
                for (int ni = 0; ni < 4; ni++)
                    acc[mi][ni] = __builtin_amdgcn_mfma_f32_16x16x32_f16(a[mi], b[ni], acc[mi][ni], 0, 0, 0);
        }
    }
    #pragma unroll
    for (int mi = 0; mi < 4; mi++) {
        #pragma unroll
        for (int r = 0; r < 4; r++) {
            int rr = wm + mi * 16 + quad * 4 + r;
            if (rr >= cnt) continue;
            size_t rowoff = ((size_t)kz * NP + row0 + rr) * D_;
            #pragma unroll
            for (int ni = 0; ni < 4; ni++)
                P.Y2p[rowoff + colbase + wn + ni * 16 + l16] = acc[mi][ni][r];
        }
    }
}

__global__ __launch_bounds__(256, 2) void moe_mega(Params P) {
    cg::grid_group grid = cg::this_grid();
    __shared__ __align__(16) char smem[32768];
    half_t* As = (half_t*)smem;
    half_t* Bs = As + 8192;
    const int blk = blockIdx.x, tid = threadIdx.x;
    const int wave = tid >> 6, lane = tid & 63;
    const int gstride = gridDim.x;

    // ================= P0: gate (wave per token) + weight fp32->f16 cvt =================
    for (int n = blk * 4 + wave; n < NTOK; n += gstride * 4) {
        const floatx4* xr = (const floatx4*)(P.inp + (size_t)n * D_);
        floatx4 x0 = xr[lane * 2], x1 = xr[lane * 2 + 1];
        float l[E_];
        #pragma unroll
        for (int e = 0; e < E_; e++) {
            const floatx4* gr = (const floatx4*)(P.gate_w + (size_t)e * D_);
            floatx4 g0 = gr[lane * 2], g1 = gr[lane * 2 + 1];
            float p = x0[0]*g0[0] + x0[1]*g0[1] + x0[2]*g0[2] + x0[3]*g0[3]
                    + x1[0]*g1[0] + x1[1]*g1[1] + x1[2]*g1[2] + x1[3]*g1[3];
            #pragma unroll
            for (int m = 1; m < 64; m <<= 1) p += __shfl_xor(p, m);
            l[e] = p + P.gate_b[e];
        }
        if (lane == 0) {
            int e0 = 0; float v0 = l[0];
            #pragma unroll
            for (int e = 1; e < E_; e++) if (l[e] > v0) { v0 = l[e]; e0 = e; }
            int e1 = -1; float v1 = -3.4e38f;
            #pragma unroll
            for (int e = 0; e < E_; e++) if (e != e0 && l[e] > v1) { v1 = l[e]; e1 = e; }
            float s1 = expf(v1 - v0);
            float den = 1.0f + s1;
            P.score[2 * n]     = 1.0f / den;
            P.score[2 * n + 1] = s1 / den;
            P.idx[2 * n]     = e0;
            P.idx[2 * n + 1] = e1;
        }
    }
    {   // cvt both weight tensors (grid-stride over 8-float groups)
        const int NG = E_ * H_ * D_ / 8;   // per tensor
        for (int i = blk * 256 + tid; i < 2 * NG; i += gstride * 256) {
            const float* src; half_t* dst; int j;
            if (i < NG) { src = P.w1; dst = P.W1h; j = i; }
            else        { src = P.w2; dst = P.W2h; j = i - NG; }
            const floatx4* s = (const floatx4*)src + (size_t)j * 2;
            floatx4 f0 = s[0], f1 = s[1];
            half8 h = { (half_t)f0[0], (half_t)f0[1], (half_t)f0[2], (half_t)f0[3],
                        (half_t)f1[0], (half_t)f1[1], (half_t)f1[2], (half_t)f1[3] };
            *(half8*)(dst + (size_t)j * 8) = h;
        }
    }
    grid.sync();

    // ================= P1: plan (block 0 only, LDS atomics) =================
    if (blk == 0) {
        int* cnt_s = (int*)smem;
        int* off_s = cnt_s + E_;
        int* cur_s = off_s + E_ + 1;
        if (tid < E_) { cnt_s[tid] = 0; cur_s[tid] = 0; }
        __syncthreads();
        int my_e[8];
        #pragma unroll
        for (int i = 0; i < 8; i++) {
            my_e[i] = P.idx[tid * 8 + i];
            atomicAdd(&cnt_s[my_e[i]], 1);
        }
        __syncthreads();
        if (tid == 0) {
            int o = 0;
            #pragma unroll
            for (int e = 0; e < E_; e++) { off_s[e] = o; o += cnt_s[e]; }
            off_s[E_] = o;
            int t = 0;
            for (int e = 0; e < E_; e++) {
                int c = cnt_s[e];
                int ntt = (c + TM - 1) / TM;
                for (int i = 0; i < ntt; i++) {
                    P.tile_e[t] = e;
                    P.tile_row0[t] = off_s[e] + i * TM;
                    int rem = c - i * TM;
                    P.tile_cnt[t] = rem < TM ? rem : TM;
                    t++;
                }
            }
            P.ntiles[0] = t;
        }
        __syncthreads();
        #pragma unroll
        for (int i = 0; i < 8; i++) {
            int e = my_e[i];
            int r = atomicAdd(&cur_s[e], 1);
            P.pos[tid * 8 + i] = off_s[e] + r;
        }
    }
    grid.sync();

    // ================= P2: scatter token rows to f16 grouped layout =================
    for (int p = blk * 4 + wave; p < NP; p += gstride * 4) {
        int pos = P.pos[p];
        int n = p >> 1;
        const floatx4* src = (const floatx4*)(P.inp + (size_t)n * D_);
        floatx4 f0 = src[lane * 2], f1 = src[lane * 2 + 1];
        half8 h = { (half_t)f0[0], (half_t)f0[1], (half_t)f0[2], (half_t)f0[3],
                    (half_t)f1[0], (half_t)f1[1], (half_t)f1[2], (half_t)f1[3] };
        *(half8*)(P.Xg + (size_t)pos * D_ + lane * 8) = h;
    }
    grid.sync();

    // ================= P3: GEMM1 =================
    {
        int nt = P.ntiles[0];
        for (int job = blk; job < nt * 16; job += gstride)
            gemm1_job(P, As, Bs, job >> 4, job & 15, tid);
    }
    grid.sync();

    // ================= P4: GEMM2 (split-K=4) =================
    {
        int nt = P.ntiles[0];
        for (int job = blk; job < nt * 16; job += gstride)
            gemm2_job(P, As, Bs, job >> 4, (job >> 2) & 3, job & 3, tid);
    }
    grid.sync();

    // ================= P5: combine + bias + LayerNorm (wave per token) =================
    for (int n = blk * 4 + wave; n < NTOK; n += gstride * 4) {
        int p0 = P.pos[2 * n], p1 = P.pos[2 * n + 1];
        int e0 = P.idx[2 * n], e1 = P.idx[2 * n + 1];
        float s0 = P.score[2 * n], s1 = P.score[2 * n + 1];

        const floatx4* b2r0 = (const floatx4*)(P.b2 + (size_t)e0 * D_);
        const floatx4* b2r1 = (const floatx4*)(P.b2 + (size_t)e1 * D_);
        floatx4 a_lo = b2r0[lane * 2], a_hi = b2r0[lane * 2 + 1];
        floatx4 c_lo = b2r1[lane * 2], c_hi = b2r1[lane * 2 + 1];
        #pragma unroll
        for (int kz = 0; kz < 4; kz++) {
            const floatx4* r0 = (const floatx4*)(P.Y2p + ((size_t)kz * NP + p0) * D_);
            const floatx4* r1 = (const floatx4*)(P.Y2p + ((size_t)kz * NP + p1) * D_);
            a_lo += r0[lane * 2]; a_hi += r0[lane * 2 + 1];
            c_lo += r1[lane * 2]; c_hi += r1[lane * 2 + 1];
        }
        floatx4 y_lo = s0 * a_lo + s1 * c_lo;
        floatx4 y_hi = s0 * a_hi + s1 * c_hi;

        float s = 0.0f, q = 0.0f;
        #pragma unroll
        for (int j = 0; j < 4; j++) {
            s += y_lo[j] + y_hi[j];
            q += y_lo[j] * y_lo[j] + y_hi[j] * y_hi[j];
        }
        #pragma unroll
        for (int m = 1; m < 64; m <<= 1) {
            s += __shfl_xor(s, m);
            q += __shfl_xor(q, m);
        }
        float mean = s * (1.0f / 512.0f);
        float var = q * (1.0f / 512.0f) - mean * mean;
        float inv = 1.0f / sqrtf(var + 1e-5f);

        const floatx4* wv = (const floatx4*)P.ln_w;
        const floatx4* bv = (const floatx4*)P.ln_b;
        floatx4 o_lo = (y_lo - mean) * inv * wv[lane * 2]     + bv[lane * 2];
        floatx4 o_hi = (y_hi - mean) * inv * wv[lane * 2 + 1] + bv[lane * 2 + 1];
        floatx4* op = (floatx4*)(P.out + (size_t)n * D_);
        op[lane * 2] = o_lo;
        op[lane * 2 + 1] = o_hi;
    }
}

extern "C" void kernel_launch(void* const* d_in, const int* in_sizes, int n_in,
                              void* d_out, int out_size, void* d_ws, size_t ws_size,
                              hipStream_t stream) {
    char* ws = (char*)d_ws;
    size_t o = 0;
    auto carve = [&](size_t bytes) -> char* {
        char* p = ws + o;
        o += (bytes + 255) & ~(size_t)255;
        return p;
    };
    Params P;
    P.inp    = (const float*)d_in[0];
    P.gate_w = (const float*)d_in[1];
    P.gate_b = (const float*)d_in[2];
    P.w1     = (const float*)d_in[3];
    P.b1     = (const float*)d_in[4];
    P.w2     = (const float*)d_in[5];
    P.b2     = (const float*)d_in[6];
    P.ln_w   = (const float*)d_in[7];
    P.ln_b   = (const float*)d_in[8];
    P.out    = (float*)d_out;
    P.W1h = (half_t*)carve(sizeof(half_t) * (size_t)E_ * H_ * D_);      // 16.8 MB
    P.W2h = (half_t*)carve(sizeof(half_t) * (size_t)E_ * D_ * H_);      // 16.8 MB
    P.Xg  = (half_t*)carve(sizeof(half_t) * (size_t)(NP + TM) * D_);    // slack for tile overrun
    P.Y1  = (half_t*)carve(sizeof(half_t) * (size_t)(NP + TM) * H_);
    P.Y2p = (float*)carve(sizeof(float) * 4 * (size_t)NP * D_);
    P.score = (float*)carve(sizeof(float) * NP);
    P.idx   = (int*)carve(sizeof(int) * NP);
    P.pos   = (int*)carve(sizeof(int) * NP);
    P.tile_e    = (int*)carve(sizeof(int) * MAX_TILES);
    P.tile_row0 = (int*)carve(sizeof(int) * MAX_TILES);
    P.tile_cnt  = (int*)carve(sizeof(int) * MAX_TILES);
    P.ntiles    = (int*)carve(sizeof(int) * 1);

    int occ = 0;
    hipOccupancyMaxActiveBlocksPerMultiprocessor(&occ, moe_mega, 256, 0);
    if (occ < 1) occ = 1;
    int nblk = occ * 256;
    if (nblk > 512) nblk = 512;

    void* kp[] = { &P };
    hipLaunchCooperativeKernel((const void*)moe_mega, dim3(nblk), dim3(256),
                               kp, 0, stream);
}

// Round 4
// 206.620 us; speedup vs baseline: 1.6799x; 1.6799x over previous
//
#include <hip/hip_runtime.h>
#include <cstdint>
#include <cstddef>

typedef _Float16 half_t;
typedef _Float16 half8 __attribute__((ext_vector_type(8)));
typedef float floatx4 __attribute__((ext_vector_type(4)));

#define E_ 8
#define D_ 512
#define H_ 2048
#define NTOK 1024
#define NP 2048            // NTOK * top_k
#define CAP 1024           // per-expert row capacity (max: each token picks an expert at most once)
#define TM 128

__device__ __forceinline__ float gelu_f(float x) {
    return 0.5f * x * (1.0f + erff(x * 0.7071067811865476f));
}

// async global->LDS, 16B/lane; LDS dest = wave-uniform base + lane*16
__device__ __forceinline__ void gload_lds16(const half_t* g, half_t* l) {
    __builtin_amdgcn_global_load_lds(
        (__attribute__((address_space(1))) void*)(g),
        (__attribute__((address_space(3))) void*)(l),
        16, 0, 0);
}

// ---------------- cvt: fp32->f16 both weight tensors; block 0 zeroes counters ----------------
__global__ __launch_bounds__(256) void cvt_kernel(
        const float* __restrict__ w1, const float* __restrict__ w2,
        half_t* __restrict__ W1h, half_t* __restrict__ W2h,
        int* __restrict__ cnt_g) {
    if (blockIdx.x == 0 && threadIdx.x < E_) cnt_g[threadIdx.x] = 0;
    const int NG = E_ * H_ * D_ / 8;   // 8-float groups per tensor
    int i = blockIdx.x * 256 + threadIdx.x;
    const float* src; half_t* dst; int j;
    if (i < NG) { src = w1; dst = W1h; j = i; }
    else        { src = w2; dst = W2h; j = i - NG; }
    const floatx4* s = (const floatx4*)src + (size_t)j * 2;
    floatx4 f0 = s[0], f1 = s[1];
    half8 h = { (half_t)f0[0], (half_t)f0[1], (half_t)f0[2], (half_t)f0[3],
                (half_t)f1[0], (half_t)f1[1], (half_t)f1[2], (half_t)f1[3] };
    *(half8*)(dst + (size_t)j * 8) = h;
}

// ---------------- gate + scatter: logits, top2, softmax, rank, f16 row to both expert slabs ----------------
__global__ __launch_bounds__(256) void gate_scatter_kernel(
        const float* __restrict__ inp, const float* __restrict__ gate_w,
        const float* __restrict__ gate_b,
        float* __restrict__ score, int* __restrict__ idx,
        int* __restrict__ pos_of_pair, int* __restrict__ cnt_g,
        half_t* __restrict__ Xg) {
    int n = blockIdx.x * 4 + (threadIdx.x >> 6);
    int lane = threadIdx.x & 63;
    const floatx4* xr = (const floatx4*)(inp + (size_t)n * D_);
    floatx4 x0 = xr[lane * 2], x1 = xr[lane * 2 + 1];
    float l[E_];
    #pragma unroll
    for (int e = 0; e < E_; e++) {
        const floatx4* gr = (const floatx4*)(gate_w + (size_t)e * D_);
        floatx4 g0 = gr[lane * 2], g1 = gr[lane * 2 + 1];
        float p = x0[0]*g0[0] + x0[1]*g0[1] + x0[2]*g0[2] + x0[3]*g0[3]
                + x1[0]*g1[0] + x1[1]*g1[1] + x1[2]*g1[2] + x1[3]*g1[3];
        #pragma unroll
        for (int m = 1; m < 64; m <<= 1) p += __shfl_xor(p, m);
        l[e] = p + gate_b[e];          // full sum present in ALL lanes
    }
    // top-2 (computed redundantly in all lanes, no divergence)
    int e0 = 0; float v0 = l[0];
    #pragma unroll
    for (int e = 1; e < E_; e++) if (l[e] > v0) { v0 = l[e]; e0 = e; }
    int e1 = -1; float v1 = -3.4e38f;
    #pragma unroll
    for (int e = 0; e < E_; e++) if (e != e0 && l[e] > v1) { v1 = l[e]; e1 = e; }
    int p0 = 0, p1 = 0;
    if (lane == 0) {
        float s1 = expf(v1 - v0);
        float den = 1.0f + s1;
        score[2 * n]     = 1.0f / den;
        score[2 * n + 1] = s1 / den;
        idx[2 * n]     = e0;
        idx[2 * n + 1] = e1;
        p0 = e0 * CAP + atomicAdd(&cnt_g[e0], 1);
        p1 = e1 * CAP + atomicAdd(&cnt_g[e1], 1);
        pos_of_pair[2 * n]     = p0;
        pos_of_pair[2 * n + 1] = p1;
    }
    p0 = __shfl(p0, 0);
    p1 = __shfl(p1, 0);
    half8 h = { (half_t)x0[0], (half_t)x0[1], (half_t)x0[2], (half_t)x0[3],
                (half_t)x1[0], (half_t)x1[1], (half_t)x1[2], (half_t)x1[3] };
    *(half8*)(Xg + (size_t)p0 * D_ + lane * 8) = h;
    *(half8*)(Xg + (size_t)p1 * D_ + lane * 8) = h;
}

// ---------------- GEMM1: Y1[e-slab] = gelu(Xg @ W1[e]^T + b1[e]) ----------------
// 128x128 tile, BK=64 as two 32-col LDS panels, 4 waves of 64x64
__global__ __launch_bounds__(256, 2) void gemm1_kernel(
        const half_t* __restrict__ Xg, const half_t* __restrict__ W1h,
        const float* __restrict__ b1, const int* __restrict__ cnt_g,
        half_t* __restrict__ Y1) {
    __shared__ half_t As[2 * 128 * 32];   // 16 KB (two 32-col panels)
    __shared__ half_t Bs[2 * 128 * 32];   // 16 KB
    int slot = blockIdx.x;
    int e = slot >> 3, ti = slot & 7;
    int valid = cnt_g[e] - ti * TM;
    if (valid <= 0) return;
    int cnt = valid < TM ? valid : TM;
    int row0 = e * CAP + ti * TM;
    int colbase = blockIdx.y * 128;
    int tid = threadIdx.x;
    int wave = tid >> 6, lane = tid & 63, quad = lane >> 4, l16 = lane & 15;
    int wm = (wave & 1) * 64, wn = (wave >> 1) * 64;
    const half_t* Abase = Xg + (size_t)row0 * D_;
    const half_t* Bbase = W1h + ((size_t)e * H_ + colbase) * D_;
    int srow = tid >> 2, scol = (tid & 3) * 8;
    floatx4 acc[4][4] = {};
    for (int k0 = 0; k0 < D_; k0 += 64) {
        __syncthreads();
        #pragma unroll
        for (int j = 0; j < 2; j++) {
            #pragma unroll
            for (int s = 0; s < 2; s++) {
                int q = tid + s * 256;
                int row = srow + s * 64;
                gload_lds16(Abase + (size_t)row * D_ + k0 + j * 32 + scol,
                            As + j * 4096 + q * 8);
                gload_lds16(Bbase + (size_t)row * D_ + k0 + j * 32 + scol,
                            Bs + j * 4096 + q * 8);
            }
        }
        __syncthreads();
        #pragma unroll
        for (int j = 0; j < 2; j++) {
            half8 a[4], b[4];
            #pragma unroll
            for (int mi = 0; mi < 4; mi++)
                a[mi] = *(const half8*)(As + j * 4096 + (wm + mi * 16 + l16) * 32 + quad * 8);
            #pragma unroll
            for (int ni = 0; ni < 4; ni++)
                b[ni] = *(const half8*)(Bs + j * 4096 + (wn + ni * 16 + l16) * 32 + quad * 8);
            #pragma unroll
            for (int mi = 0; mi < 4; mi++)
                #pragma unroll
                for (int ni = 0; ni < 4; ni++)
                    acc[mi][ni] = __builtin_amdgcn_mfma_f32_16x16x32_f16(a[mi], b[ni], acc[mi][ni], 0, 0, 0);
        }
    }
    float bias[4];
    #pragma unroll
    for (int ni = 0; ni < 4; ni++)
        bias[ni] = b1[(size_t)e * H_ + colbase + wn + ni * 16 + l16];
    #pragma unroll
    for (int mi = 0; mi < 4; mi++) {
        #pragma unroll
        for (int r = 0; r < 4; r++) {
            int rr = wm + mi * 16 + quad * 4 + r;
            if (rr >= cnt) continue;
            size_t rowoff = (size_t)(row0 + rr) * H_;
            #pragma unroll
            for (int ni = 0; ni < 4; ni++) {
                float v = acc[mi][ni][r] + bias[ni];
                Y1[rowoff + colbase + wn + ni * 16 + l16] = (half_t)gelu_f(v);
            }
        }
    }
}

// ---------------- GEMM2 (split-K=4): Y2p[kz] = Y1 @ W2[e]^T ----------------
__global__ __launch_bounds__(256, 2) void gemm2_kernel(
        const half_t* __restrict__ Y1, const half_t* __restrict__ W2h,
        const int* __restrict__ cnt_g, float* __restrict__ Y2p) {
    __shared__ half_t As[2 * 128 * 32];
    __shared__ half_t Bs[2 * 128 * 32];
    int slot = blockIdx.x;
    int e = slot >> 3, ti = slot & 7;
    int valid = cnt_g[e] - ti * TM;
    if (valid <= 0) return;
    int cnt = valid < TM ? valid : TM;
    int row0 = e * CAP + ti * TM;
    int colbase = blockIdx.y * 128;
    int kz = blockIdx.z;
    int kzb = kz * 512;
    int tid = threadIdx.x;
    int wave = tid >> 6, lane = tid & 63, quad = lane >> 4, l16 = lane & 15;
    int wm = (wave & 1) * 64, wn = (wave >> 1) * 64;
    const half_t* Abase = Y1 + (size_t)row0 * H_ + kzb;
    const half_t* Bbase = W2h + ((size_t)e * D_ + colbase) * H_ + kzb;
    int srow = tid >> 2, scol = (tid & 3) * 8;
    floatx4 acc[4][4] = {};
    for (int k0 = 0; k0 < 512; k0 += 64) {
        __syncthreads();
        #pragma unroll
        for (int j = 0; j < 2; j++) {
            #pragma unroll
            for (int s = 0; s < 2; s++) {
                int q = tid + s * 256;
                int row = srow + s * 64;
                gload_lds16(Abase + (size_t)row * H_ + k0 + j * 32 + scol,
                            As + j * 4096 + q * 8);
                gload_lds16(Bbase + (size_t)row * H_ + k0 + j * 32 + scol,
                            Bs + j * 4096 + q * 8);
            }
        }
        __syncthreads();
        #pragma unroll
        for (int j = 0; j < 2; j++) {
            half8 a[4], b[4];
            #pragma unroll
            for (int mi = 0; mi < 4; mi++)
                a[mi] = *(const half8*)(As + j * 4096 + (wm + mi * 16 + l16) * 32 + quad * 8);
            #pragma unroll
            for (int ni = 0; ni < 4; ni++)
                b[ni] = *(const half8*)(Bs + j * 4096 + (wn + ni * 16 + l16) * 32 + quad * 8);
            #pragma unroll
            for (int mi = 0; mi < 4; mi++)
                #pragma unroll
                for (int ni = 0; ni < 4; ni++)
                    acc[mi][ni] = __builtin_amdgcn_mfma_f32_16x16x32_f16(a[mi], b[ni], acc[mi][ni], 0, 0, 0);
        }
    }
    #pragma unroll
    for (int mi = 0; mi < 4; mi++) {
        #pragma unroll
        for (int r = 0; r < 4; r++) {
            int rr = wm + mi * 16 + quad * 4 + r;
            if (rr >= cnt) continue;
            size_t rowoff = ((size_t)kz * (E_ * CAP) + row0 + rr) * D_;
            #pragma unroll
            for (int ni = 0; ni < 4; ni++)
                Y2p[rowoff + colbase + wn + ni * 16 + l16] = acc[mi][ni][r];
        }
    }
}

// ---------------- combine + bias + LayerNorm, wave per token ----------------
__global__ __launch_bounds__(256) void final_kernel(
        const float* __restrict__ Y2p, const float* __restrict__ b2,
        const int* __restrict__ idx, const float* __restrict__ score,
        const int* __restrict__ pos_of_pair,
        const float* __restrict__ ln_w, const float* __restrict__ ln_b,
        float* __restrict__ out) {
    int n = blockIdx.x * 4 + (threadIdx.x >> 6);
    int lane = threadIdx.x & 63;
    int p0 = pos_of_pair[2 * n], p1 = pos_of_pair[2 * n + 1];
    int e0 = idx[2 * n], e1 = idx[2 * n + 1];
    float s0 = score[2 * n], s1 = score[2 * n + 1];

    const floatx4* b2r0 = (const floatx4*)(b2 + (size_t)e0 * D_);
    const floatx4* b2r1 = (const floatx4*)(b2 + (size_t)e1 * D_);
    floatx4 a_lo = b2r0[lane * 2], a_hi = b2r0[lane * 2 + 1];
    floatx4 c_lo = b2r1[lane * 2], c_hi = b2r1[lane * 2 + 1];
    #pragma unroll
    for (int kz = 0; kz < 4; kz++) {
        const floatx4* r0 = (const floatx4*)(Y2p + ((size_t)kz * (E_ * CAP) + p0) * D_);
        const floatx4* r1 = (const floatx4*)(Y2p + ((size_t)kz * (E_ * CAP) + p1) * D_);
        a_lo += r0[lane * 2]; a_hi += r0[lane * 2 + 1];
        c_lo += r1[lane * 2]; c_hi += r1[lane * 2 + 1];
    }
    floatx4 y_lo = s0 * a_lo + s1 * c_lo;
    floatx4 y_hi = s0 * a_hi + s1 * c_hi;

    float s = 0.0f, q = 0.0f;
    #pragma unroll
    for (int j = 0; j < 4; j++) {
        s += y_lo[j] + y_hi[j];
        q += y_lo[j] * y_lo[j] + y_hi[j] * y_hi[j];
    }
    #pragma unroll
    for (int m = 1; m < 64; m <<= 1) {
        s += __shfl_xor(s, m);
        q += __shfl_xor(q, m);
    }
    float mean = s * (1.0f / 512.0f);
    float var = q * (1.0f / 512.0f) - mean * mean;
    float inv = 1.0f / sqrtf(var + 1e-5f);

    const floatx4* wv = (const floatx4*)ln_w;
    const floatx4* bv = (const floatx4*)ln_b;
    floatx4 o_lo = (y_lo - mean) * inv * wv[lane * 2]     + bv[lane * 2];
    floatx4 o_hi = (y_hi - mean) * inv * wv[lane * 2 + 1] + bv[lane * 2 + 1];
    floatx4* op = (floatx4*)(out + (size_t)n * D_);
    op[lane * 2] = o_lo;
    op[lane * 2 + 1] = o_hi;
}

extern "C" void kernel_launch(void* const* d_in, const int* in_sizes, int n_in,
                              void* d_out, int out_size, void* d_ws, size_t ws_size,
                              hipStream_t stream) {
    const float* inp    = (const float*)d_in[0];
    const float* gate_w = (const float*)d_in[1];
    const float* gate_b = (const float*)d_in[2];
    const float* w1     = (const float*)d_in[3];
    const float* b1     = (const float*)d_in[4];
    const float* w2     = (const float*)d_in[5];
    const float* b2     = (const float*)d_in[6];
    const float* ln_w   = (const float*)d_in[7];
    const float* ln_b   = (const float*)d_in[8];
    float* out = (float*)d_out;

    char* ws = (char*)d_ws;
    size_t o = 0;
    auto carve = [&](size_t bytes) -> char* {
        char* p = ws + o;
        o += (bytes + 255) & ~(size_t)255;
        return p;
    };
    half_t* W1h = (half_t*)carve(sizeof(half_t) * (size_t)E_ * H_ * D_);          // 16 MB
    half_t* W2h = (half_t*)carve(sizeof(half_t) * (size_t)E_ * D_ * H_);          // 16 MB
    half_t* Xg  = (half_t*)carve(sizeof(half_t) * (size_t)E_ * CAP * D_);         // 8 MB
    half_t* Y1  = (half_t*)carve(sizeof(half_t) * (size_t)E_ * CAP * H_);         // 32 MB
    float*  Y2p = (float*)carve(sizeof(float) * 4 * (size_t)E_ * CAP * D_);       // 64 MB
    float*  score = (float*)carve(sizeof(float) * NP);
    int* idx         = (int*)carve(sizeof(int) * NP);
    int* pos_of_pair = (int*)carve(sizeof(int) * NP);
    int* cnt_g       = (int*)carve(sizeof(int) * E_);

    cvt_kernel<<<2 * E_ * H_ * D_ / 8 / 256, 256, 0, stream>>>(w1, w2, W1h, W2h, cnt_g);
    gate_scatter_kernel<<<NTOK / 4, 256, 0, stream>>>(inp, gate_w, gate_b,
                                                      score, idx, pos_of_pair, cnt_g, Xg);
    gemm1_kernel<<<dim3(E_ * (CAP / TM), H_ / 128), 256, 0, stream>>>(
        Xg, W1h, b1, cnt_g, Y1);
    gemm2_kernel<<<dim3(E_ * (CAP / TM), D_ / 128, 4), 256, 0, stream>>>(
        Y1, W2h, cnt_g, Y2p);
    final_kernel<<<NTOK / 4, 256, 0, stream>>>(Y2p, b2, idx, score, pos_of_pair, ln_w, ln_b, out);
}